// Round 1
// 234.553 us; speedup vs baseline: 1.0266x; 1.0266x over previous
//
#include <hip/hip_runtime.h>

typedef unsigned short u16;
typedef unsigned int u32;
typedef short s16x8 __attribute__((ext_vector_type(8)));
typedef short s16x4 __attribute__((ext_vector_type(4)));
typedef float f32x4 __attribute__((ext_vector_type(4)));
typedef u32 u32x2 __attribute__((ext_vector_type(2)));

#define AS1 __attribute__((address_space(1)))
#define AS3 __attribute__((address_space(3)))

__device__ __forceinline__ float bf2f(u16 u) {
    union { unsigned int i; float f; } x; x.i = ((unsigned int)u) << 16; return x.f;
}
__device__ __forceinline__ u16 f2bf(float f) {
    union { float f; unsigned int i; } x; x.f = f;
    unsigned int r = (x.i + 0x7FFFu + ((x.i >> 16) & 1u)) >> 16;
    return (u16)r;
}
__device__ __forceinline__ void storeOut(u16* p, float v) { *p = f2bf(v); }
__device__ __forceinline__ void storeOut(float* p, float v) { *p = v; }
__device__ __forceinline__ float loadIn(const void* p, size_t i, int isf32) {
    return isf32 ? ((const float*)p)[i] : bf2f(((const u16*)p)[i]);
}
__device__ __forceinline__ float fexp2(float x) {
#if __has_builtin(__builtin_amdgcn_exp2f)
    return __builtin_amdgcn_exp2f(x);
#else
    return exp2f(x);
#endif
}
// pack two f32 -> bf16x2 (round-half-up): low half = a, high half = b
__device__ __forceinline__ u32 pack_bf(float a, float b) {
    u32 ua = __float_as_uint(a) + 0x8000u;
    u32 ub = __float_as_uint(b) + 0x8000u;
    return __builtin_amdgcn_perm(ub, ua, 0x07060302u);
}

// ---------------- runtime dtype detector ---------------------------------------------
__global__ __launch_bounds__(256) void detect_dtype(const u16* __restrict__ x,
                                                    int* __restrict__ flag) {
    __shared__ int cnt[4];
    const int tid = threadIdx.x;
    int c = 0;
    #pragma unroll
    for (int i = 0; i < 4; ++i) {
        const u16 u = x[tid * 4 + i];
        const int e = (u >> 7) & 0xFF;
        c += (e >= 101 && e <= 135) ? 1 : 0;
    }
    #pragma unroll
    for (int m = 1; m < 64; m <<= 1) c += __shfl_xor(c, m, 64);
    if ((tid & 63) == 0) cnt[tid >> 6] = c;
    __syncthreads();
    if (tid == 0) {
        const int t = cnt[0] + cnt[1] + cnt[2] + cnt[3];
        *flag = (t < 800) ? 1 : 0;   // 1 = inputs are float32
    }
}

// ---------------- cond @ w_cond (split-K GEMV, atomicAdd into zeroed f32 ws) ----------
__global__ __launch_bounds__(256) void cond_gemv(const void* __restrict__ cond,
                                                 const void* __restrict__ w,
                                                 float* __restrict__ out,
                                                 const int* __restrict__ flag) {
    const int isf32 = *flag;
    const int d  = blockIdx.x * 256 + threadIdx.x;
    const int n  = blockIdx.y;
    const int k0 = blockIdx.z * 64;
    float acc = 0.f;
    #pragma unroll 8
    for (int k = 0; k < 64; ++k)
        acc += loadIn(cond, n * 1024 + k0 + k, isf32) *
               loadIn(w, (size_t)(k0 + k) * 1024 + d, isf32);
    atomicAdd(out + n * 1024 + d, acc);
}

// ---------------- RMS norm of x with scale = (cond@w_cond + 1) -----------------------
__global__ __launch_bounds__(256) void rmsnorm_x(const void* __restrict__ x,
                                                 const float* __restrict__ scl,
                                                 u16* __restrict__ xn,
                                                 const int* __restrict__ flag) {
    const int isf32 = *flag;
    const int tok = blockIdx.x;
    const int n = tok >> 11;
    u16* orow = xn + (size_t)tok * 1024;
    const int base = threadIdx.x * 4;
    float f0, f1, f2, f3;
    if (isf32) {
        const float4 v = *(const float4*)((const float*)x + (size_t)tok * 1024 + base);
        f0 = v.x; f1 = v.y; f2 = v.z; f3 = v.w;
    } else {
        s16x4 uv = *(const s16x4*)((const u16*)x + (size_t)tok * 1024 + base);
        f0 = bf2f((u16)uv[0]); f1 = bf2f((u16)uv[1]); f2 = bf2f((u16)uv[2]); f3 = bf2f((u16)uv[3]);
    }
    float ss = f0 * f0 + f1 * f1 + f2 * f2 + f3 * f3;
    #pragma unroll
    for (int m = 1; m < 64; m <<= 1) ss += __shfl_xor(ss, m, 64);
    __shared__ float red[4];
    const int wave = threadIdx.x >> 6, lane = threadIdx.x & 63;
    if (lane == 0) red[wave] = ss;
    __syncthreads();
    float ms = (red[0] + red[1] + red[2] + red[3]) * (1.f / 1024.f);
    float rinv = rsqrtf(ms + 1e-6f);
    orow[base + 0] = f2bf(f0 * (scl[n * 1024 + base + 0] + 1.f) * rinv);
    orow[base + 1] = f2bf(f1 * (scl[n * 1024 + base + 1] + 1.f) * rinv);
    orow[base + 2] = f2bf(f2 * (scl[n * 1024 + base + 2] + 1.f) * rinv);
    orow[base + 3] = f2bf(f3 * (scl[n * 1024 + base + 3] + 1.f) * rinv);
}

// ---------------- transpose (src R x C -> dst C x R), dual-dtype read, bf16 out ------
__global__ __launch_bounds__(256) void transpose_bf(const void* __restrict__ src,
                                                    u16* __restrict__ dst, int R, int C,
                                                    const int* __restrict__ flag) {
    const int isf32 = *flag;
    __shared__ u16 t[32][33];
    const int c0 = blockIdx.x * 32, r0 = blockIdx.y * 32;
    const int tx = threadIdx.x & 31, ty = threadIdx.x >> 5;
    #pragma unroll
    for (int i = 0; i < 4; ++i)
        t[ty + i * 8][tx] = f2bf(loadIn(src, (size_t)(r0 + ty + i * 8) * C + c0 + tx, isf32));
    __syncthreads();
    #pragma unroll
    for (int i = 0; i < 4; ++i)
        dst[(size_t)(c0 + ty + i * 8) * R + r0 + tx] = t[tx][ty + i * 8];
}

// ---------------- bf16 GEMM: C[M,N] = A[M,K] * BT[N,K]^T, 128x128 tile, BK=32 --------
template <typename OutT>
__global__ __launch_bounds__(256) void gemm_bt(const u16* __restrict__ A,
                                               const u16* __restrict__ BT,
                                               OutT* __restrict__ C, int Nn, int K) {
    __shared__ u16 As[128 * 32];
    __shared__ u16 Bs[128 * 32];
    const int tid = threadIdx.x;
    const int wave = tid >> 6, lane = tid & 63;
    const int l15 = lane & 15, quad = lane >> 4;
    const int bm0 = blockIdx.y * 128, bn0 = blockIdx.x * 128;
    const int wr = wave >> 1, wc = wave & 1;
    f32x4 acc[4][4] = {};
    const int srow = lane >> 2;
    const int g = (lane & 3) ^ (srow & 3);
    for (int bk = 0; bk < K; bk += 32) {
        __syncthreads();
        #pragma unroll
        for (int p = 0; p < 2; ++p) {
            const int rowl = p * 64 + wave * 16 + srow;
            const u16* ga = A + (size_t)(bm0 + rowl) * K + bk + g * 8;
            u16* la = As + (p * 64 + wave * 16) * 32;
            __builtin_amdgcn_global_load_lds((const AS1 void*)ga, (AS3 void*)la, 16, 0, 0);
            const u16* gb = BT + (size_t)(bn0 + rowl) * K + bk + g * 8;
            u16* lb = Bs + (p * 64 + wave * 16) * 32;
            __builtin_amdgcn_global_load_lds((const AS1 void*)gb, (AS3 void*)lb, 16, 0, 0);
        }
        __syncthreads();
        s16x8 af[4], bfr[4];
        #pragma unroll
        for (int mt = 0; mt < 4; ++mt) {
            const int r = wr * 64 + mt * 16 + l15;
            af[mt] = *(const s16x8*)(As + r * 32 + ((quad ^ (r & 3)) << 3));
        }
        #pragma unroll
        for (int nt = 0; nt < 4; ++nt) {
            const int r = wc * 64 + nt * 16 + l15;
            bfr[nt] = *(const s16x8*)(Bs + r * 32 + ((quad ^ (r & 3)) << 3));
        }
        #pragma unroll
        for (int mt = 0; mt < 4; ++mt)
            #pragma unroll
            for (int nt = 0; nt < 4; ++nt)
                acc[mt][nt] = __builtin_amdgcn_mfma_f32_16x16x32_bf16(af[mt], bfr[nt], acc[mt][nt], 0, 0, 0);
    }
    #pragma unroll
    for (int mt = 0; mt < 4; ++mt)
        #pragma unroll
        for (int nt = 0; nt < 4; ++nt)
            #pragma unroll
            for (int r = 0; r < 4; ++r) {
                const int row = bm0 + wr * 64 + mt * 16 + quad * 4 + r;
                const int col = bn0 + wc * 64 + nt * 16 + l15;
                storeOut(C + (size_t)row * Nn + col, acc[mt][nt][r]);
            }
}

// ---------------- fused per-head q/k RMS+RoPE + V transpose --------------------------
// grid (32 l-tiles, 32 nh), 256 thr. Wave handles 16 tokens (one per iter, lane = e).
// q scaled by s^2/8 * log2(e) so attention softmax uses exp2 with fixed shift.
__global__ __launch_bounds__(256) void qkv_head(const u16* __restrict__ qkv,
                                                const void* __restrict__ pos,
                                                const void* __restrict__ qk_scale,
                                                u16* __restrict__ q_ws,
                                                u16* __restrict__ k_ws,
                                                u16* __restrict__ vtg,
                                                const int* __restrict__ flag) {
    const int isf32 = *flag;
    const int nh = blockIdx.y;
    const int n = nh >> 4, h = nh & 15;
    const int l0 = blockIdx.x * 64;
    const int tid = threadIdx.x;
    const int wave = tid >> 6, lane = tid & 63;

    // per-lane constants (hoisted out of the token loop)
    const float qs = loadIn(qk_scale, h, isf32);
    const float s = __expf(0.5f * fminf(qs, 4.605170186f) - 1.039720771f);
    const float qmul = s * s * 0.125f * 1.44269504089f;
    const int j = lane & 31;
    const float t = (float)((j & 15) * 16 + h);
    const float freq = 3.14159265358979f * __expf(t * (2.302585093f / 256.f));
    const int pj = j >> 4;

    #pragma unroll 2
    for (int it = 0; it < 16; ++it) {
        const int l = l0 + wave * 16 + it;
        const int tok = n * 2048 + l;
        const u16* row = qkv + (size_t)tok * 3072;
        float qv = bf2f(row[h * 64 + lane]);
        float kv = bf2f(row[1024 + h * 64 + lane]);
        float q2 = qv * qv, k2 = kv * kv;
        #pragma unroll
        for (int m = 1; m < 64; m <<= 1) { q2 += __shfl_xor(q2, m, 64); k2 += __shfl_xor(k2, m, 64); }
        float qn = qv * rsqrtf(q2 * (1.f / 64.f) + 1e-6f) * qmul;
        float kn = kv * rsqrtf(k2 * (1.f / 64.f) + 1e-6f);
        const float p = loadIn(pos, tok * 2 + pj, isf32);
        const float th = p * freq;
        const float c = __cosf(th), sn = __sinf(th);
        const float pq = __shfl_xor(qn, 32, 64);
        const float pk = __shfl_xor(kn, 32, 64);
        float qr, kr;
        if (lane < 32) { qr = qn * c - pq * sn; kr = kn * c - pk * sn; }
        else           { qr = qn * c + pq * sn; kr = kn * c + pk * sn; }
        const size_t oidx = ((size_t)nh * 2048 + l) * 64 + lane;
        q_ws[oidx] = f2bf(qr);
        k_ws[oidx] = f2bf(kr);
    }

    // V transpose: 64 l x 64 e tile -> vtg[nh][e][l]
    __shared__ u16 tbuf[64][65];
    const u16* vsrc = qkv + (size_t)(n * 2048 + l0) * 3072 + 2048 + h * 64;
    #pragma unroll
    for (int it = 0; it < 16; ++it) {
        const int idx = it * 256 + tid;
        const int r = idx >> 6, c = idx & 63;
        tbuf[r][c] = vsrc[(size_t)r * 3072 + c];
    }
    __syncthreads();
    u16* dst = vtg + (size_t)nh * 131072 + l0;
    #pragma unroll
    for (int it = 0; it < 16; ++it) {
        const int idx = it * 256 + tid;
        const int er = idx >> 6, lc = idx & 63;
        dst[(size_t)er * 2048 + lc] = tbuf[lc][er];
    }
}

// ---------------- flash attention v6: 8 waves, 16 q-rows/wave, P pipelined -----------
// 512 thr (8 waves), q-tile 128, k-tile 64, 32 iters. Same total work per block as v5
// but 2x the waves -> 16 waves/CU (4/SIMD) to hide exp2/LDS/barrier latency
// (v5 counters: MfmaUtil 23 + VALUBusy 37, Occupancy 19% -> latency-bound at 2 w/SIMD).
// Per iter: prefetch K/V(i+1) (1 K + 1 V load per wave) -> read P(i-1) frags -> QK(i)
// -> PV(i-1) -> softmax(i) -> write P(i) -> barrier.
// K dbuf, V tri-buffer, P wave-private [16][72]. LDS 58 KB -> 2 blocks/CU.
// QK acc init -15 = softmax shift folded into exp2.
__global__ __launch_bounds__(512, 4) void attn6(const u16* __restrict__ Q,
                                                const u16* __restrict__ K,
                                                const u16* __restrict__ Vtg,
                                                u16* __restrict__ O) {
    __shared__ u16 Ks[2][64 * 64];
    __shared__ u16 Vt[3][64 * 64];
    __shared__ u16 Ps[8][16 * 72];
    const int nh = blockIdx.y;
    const int q0 = blockIdx.x * 128;
    const int tid = threadIdx.x;
    const int wave = tid >> 6, lane = tid & 63;
    const int l15 = lane & 15, quad = lane >> 4;
    const size_t hb = (size_t)nh * 2048 * 64;
    const u16* Vbase = Vtg + (size_t)nh * 131072;
    const int dr0 = tid >> 3;            // DMA row 0..63 (one row-chunk per lane-octet)
    const int dd  = tid & 7;             // DMA chunk
    const int dg  = dd ^ (dr0 & 7);      // swizzled source chunk

    s16x8 qf[2];
    #pragma unroll
    for (int kc = 0; kc < 2; ++kc)
        qf[kc] = *(const s16x8*)(Q + hb + (size_t)(q0 + wave * 16 + l15) * 64 + kc * 32 + quad * 8);

    f32x4 Oacc[4] = {};
    float lacc = 0.f;
    u16* Pw = Ps[wave];

    // preload tile 0: each wave stages 8 rows of K and of V^T (64 lanes x 16B = 1 KB)
    __builtin_amdgcn_global_load_lds(
        (const AS1 void*)(K + hb + (size_t)dr0 * 64 + dg * 8),
        (AS3 void*)(Ks[0] + wave * 512), 16, 0, 0);
    __builtin_amdgcn_global_load_lds(
        (const AS1 void*)(Vbase + (size_t)dr0 * 2048 + dg * 8),
        (AS3 void*)(Vt[0] + wave * 512), 16, 0, 0);
    __syncthreads();

    int vprev = 2, vcur = 0, vnxt = 1;
    s16x8 pf[2];   // [kc]

    for (int i = 0; i < 32; ++i) {
        const int kcur = i & 1;
        // ---- prefetch tile i+1 (no waits) ----
        if (i < 31) {
            const int kbn = (i + 1) * 64;
            __builtin_amdgcn_global_load_lds(
                (const AS1 void*)(K + hb + (size_t)(kbn + dr0) * 64 + dg * 8),
                (AS3 void*)(Ks[kcur ^ 1] + wave * 512), 16, 0, 0);
            __builtin_amdgcn_global_load_lds(
                (const AS1 void*)(Vbase + (size_t)dr0 * 2048 + kbn + dg * 8),
                (AS3 void*)(Vt[vnxt] + wave * 512), 16, 0, 0);
        }
        // ---- read P(i-1) fragments (before overwriting; same-wave LDS order) ----
        if (i > 0) {
            pf[0] = *(const s16x8*)(Pw + l15 * 72 + quad * 8);
            pf[1] = *(const s16x8*)(Pw + l15 * 72 + 32 + quad * 8);
        }
        // ---- QK(i): S^T = K*Q^T, acc init -15 (softmax shift folded) ----
        f32x4 S[4];
        #pragma unroll
        for (int kt = 0; kt < 4; ++kt) {
            S[kt][0] = -15.f; S[kt][1] = -15.f;
            S[kt][2] = -15.f; S[kt][3] = -15.f;
        }
        #pragma unroll
        for (int kt = 0; kt < 4; ++kt) {
            const int r = kt * 16 + l15;
            #pragma unroll
            for (int kc = 0; kc < 2; ++kc) {
                const s16x8 kf = *(const s16x8*)(Ks[kcur] + r * 64 + (((kc * 4 + quad) ^ (r & 7)) << 3));
                S[kt] = __builtin_amdgcn_mfma_f32_16x16x32_bf16(kf, qf[kc], S[kt], 0, 0, 0);
            }
        }
        // ---- PV(i-1): independent of QK(i)/softmax — interleaves ----
        if (i > 0) {
            #pragma unroll
            for (int kc = 0; kc < 2; ++kc)
                #pragma unroll
                for (int nto = 0; nto < 4; ++nto) {
                    const int e = nto * 16 + l15;
                    const s16x8 vf = *(const s16x8*)(Vt[vprev] + e * 64 + (((kc * 4 + quad) ^ (e & 7)) << 3));
                    Oacc[nto] = __builtin_amdgcn_mfma_f32_16x16x32_bf16(pf[kc], vf, Oacc[nto], 0, 0, 0);
                }
        }
        // ---- softmax(i): exp2, accumulate l, write P(i) ----
        {
            float rs = 0.f;
            #pragma unroll
            for (int kt = 0; kt < 4; ++kt) {
                const float e0 = fexp2(S[kt][0]);
                const float e1 = fexp2(S[kt][1]);
                const float e2 = fexp2(S[kt][2]);
                const float e3 = fexp2(S[kt][3]);
                rs += (e0 + e1) + (e2 + e3);
                u32x2 pk2;
                pk2[0] = pack_bf(e0, e1);
                pk2[1] = pack_bf(e2, e3);
                *(u32x2*)(Pw + l15 * 72 + kt * 16 + quad * 4) = pk2;
            }
            lacc += rs;
        }
        // rotate V buffers
        const int tmp = vprev; vprev = vcur; vcur = vnxt; vnxt = tmp;
        if (i < 31) __syncthreads();
    }

    // ---- epilogue: PV(31); V(31) is in Vt[vprev] after final rotation ----
    pf[0] = *(const s16x8*)(Pw + l15 * 72 + quad * 8);
    pf[1] = *(const s16x8*)(Pw + l15 * 72 + 32 + quad * 8);
    #pragma unroll
    for (int kc = 0; kc < 2; ++kc)
        #pragma unroll
        for (int nto = 0; nto < 4; ++nto) {
            const int e = nto * 16 + l15;
            const s16x8 vf = *(const s16x8*)(Vt[vprev] + e * 64 + (((kc * 4 + quad) ^ (e & 7)) << 3));
            Oacc[nto] = __builtin_amdgcn_mfma_f32_16x16x32_bf16(pf[kc], vf, Oacc[nto], 0, 0, 0);
        }

    lacc += __shfl_xor(lacc, 16, 64);
    lacc += __shfl_xor(lacc, 32, 64);

    const int n = nh >> 4, h = nh & 15;
    #pragma unroll
    for (int r = 0; r < 4; ++r) {
        const float linv = 1.f / __shfl(lacc, quad * 4 + r, 64);
        const int qrow = q0 + wave * 16 + quad * 4 + r;
        #pragma unroll
        for (int nto = 0; nto < 4; ++nto)
            O[((size_t)n * 2048 + qrow) * 1024 + h * 64 + nto * 16 + l15] = f2bf(Oacc[nto][r] * linv);
    }
}

// ---------------- launch --------------------------------------------------------------
extern "C" void kernel_launch(void* const* d_in, const int* in_sizes, int n_in,
                              void* d_out, int out_size, void* d_ws, size_t ws_size,
                              hipStream_t stream) {
    const void* x        = d_in[0];
    const void* pos      = d_in[1];
    const void* cond     = d_in[2];
    const void* w_cond   = d_in[3];
    const void* w_qkv    = d_in[4];
    const void* qk_scale = d_in[5];
    const void* w_out    = d_in[6];

    char* ws = (char*)d_ws;
    constexpr size_t OFS_SCALE = 0;
    constexpr size_t OFS_FLAG  = 8192;
    constexpr size_t OFS_XN    = 16384;
    constexpr size_t OFS_WQKVT = OFS_XN    + 8388608;
    constexpr size_t OFS_WOUTT = OFS_WQKVT + 6291456;
    constexpr size_t OFS_QKV   = OFS_WOUTT + 2097152;
    constexpr size_t OFS_Q     = OFS_QKV   + 25165824;
    constexpr size_t OFS_K     = OFS_Q     + 8388608;
    constexpr size_t OFS_VT    = OFS_K     + 8388608;
    constexpr size_t OFS_O     = OFS_VT    + 8388608;

    float* scale = (float*)(ws + OFS_SCALE);
    int*   flag  = (int*)(ws + OFS_FLAG);
    u16* xn    = (u16*)(ws + OFS_XN);
    u16* wqkvT = (u16*)(ws + OFS_WQKVT);
    u16* woutT = (u16*)(ws + OFS_WOUTT);
    u16* qkv   = (u16*)(ws + OFS_QKV);
    u16* qws   = (u16*)(ws + OFS_Q);
    u16* kws   = (u16*)(ws + OFS_K);
    u16* vtg   = (u16*)(ws + OFS_VT);
    u16* ows   = (u16*)(ws + OFS_O);

    detect_dtype<<<dim3(1), 256, 0, stream>>>((const u16*)x, flag);
    hipMemsetAsync(scale, 0, 2 * 1024 * sizeof(float), stream);
    cond_gemv<<<dim3(4, 2, 16), 256, 0, stream>>>(cond, w_cond, scale, flag);
    rmsnorm_x<<<dim3(4096), 256, 0, stream>>>(x, scale, xn, flag);
    transpose_bf<<<dim3(96, 32), 256, 0, stream>>>(w_qkv, wqkvT, 1024, 3072, flag);
    transpose_bf<<<dim3(32, 32), 256, 0, stream>>>(w_out, woutT, 1024, 1024, flag);
    gemm_bt<u16><<<dim3(24, 32), 256, 0, stream>>>(xn, wqkvT, qkv, 3072, 1024);
    qkv_head<<<dim3(32, 32), 256, 0, stream>>>(qkv, pos, qk_scale, qws, kws, vtg, flag);
    attn6<<<dim3(16, 32), 512, 0, stream>>>(qws, kws, vtg, ows);
    gemm_bt<float><<<dim3(8, 32), 256, 0, stream>>>(ows, woutT, (float*)d_out, 1024, 1024);
}

// Round 3
// 231.592 us; speedup vs baseline: 1.0397x; 1.0128x over previous
//
#include <hip/hip_runtime.h>

typedef unsigned short u16;
typedef unsigned int u32;
typedef short s16x8 __attribute__((ext_vector_type(8)));
typedef short s16x4 __attribute__((ext_vector_type(4)));
typedef float f32x4 __attribute__((ext_vector_type(4)));
typedef float f32x16 __attribute__((ext_vector_type(16)));

#define AS1 __attribute__((address_space(1)))
#define AS3 __attribute__((address_space(3)))

__device__ __forceinline__ float bf2f(u16 u) {
    union { unsigned int i; float f; } x; x.i = ((unsigned int)u) << 16; return x.f;
}
__device__ __forceinline__ u16 f2bf(float f) {
    union { float f; unsigned int i; } x; x.f = f;
    unsigned int r = (x.i + 0x7FFFu + ((x.i >> 16) & 1u)) >> 16;
    return (u16)r;
}
__device__ __forceinline__ void storeOut(u16* p, float v) { *p = f2bf(v); }
__device__ __forceinline__ void storeOut(float* p, float v) { *p = v; }
__device__ __forceinline__ float loadIn(const void* p, size_t i, int isf32) {
    return isf32 ? ((const float*)p)[i] : bf2f(((const u16*)p)[i]);
}
__device__ __forceinline__ float fexp2(float x) {
#if __has_builtin(__builtin_amdgcn_exp2f)
    return __builtin_amdgcn_exp2f(x);
#else
    return exp2f(x);
#endif
}
// exchange upper half-lanes of a with lower half-lanes of b (v_permlane32_swap_b32)
__device__ __forceinline__ void plswap(u32& a, u32& b) {
#if __has_builtin(__builtin_amdgcn_permlane32_swap)
    const auto r = __builtin_amdgcn_permlane32_swap(a, b, false, false);
    a = (u32)r[0]; b = (u32)r[1];
#else
    asm("v_permlane32_swap_b32 %0, %1" : "+v"(a), "+v"(b));
#endif
}

// ---------------- runtime dtype detector ---------------------------------------------
__global__ __launch_bounds__(256) void detect_dtype(const u16* __restrict__ x,
                                                    int* __restrict__ flag) {
    __shared__ int cnt[4];
    const int tid = threadIdx.x;
    int c = 0;
    #pragma unroll
    for (int i = 0; i < 4; ++i) {
        const u16 u = x[tid * 4 + i];
        const int e = (u >> 7) & 0xFF;
        c += (e >= 101 && e <= 135) ? 1 : 0;
    }
    #pragma unroll
    for (int m = 1; m < 64; m <<= 1) c += __shfl_xor(c, m, 64);
    if ((tid & 63) == 0) cnt[tid >> 6] = c;
    __syncthreads();
    if (tid == 0) {
        const int t = cnt[0] + cnt[1] + cnt[2] + cnt[3];
        *flag = (t < 800) ? 1 : 0;   // 1 = inputs are float32
    }
}

// ---------------- cond @ w_cond (split-K GEMV, atomicAdd into zeroed f32 ws) ----------
__global__ __launch_bounds__(256) void cond_gemv(const void* __restrict__ cond,
                                                 const void* __restrict__ w,
                                                 float* __restrict__ out,
                                                 const int* __restrict__ flag) {
    const int isf32 = *flag;
    const int d  = blockIdx.x * 256 + threadIdx.x;
    const int n  = blockIdx.y;
    const int k0 = blockIdx.z * 64;
    float acc = 0.f;
    #pragma unroll 8
    for (int k = 0; k < 64; ++k)
        acc += loadIn(cond, n * 1024 + k0 + k, isf32) *
               loadIn(w, (size_t)(k0 + k) * 1024 + d, isf32);
    atomicAdd(out + n * 1024 + d, acc);
}

// ---------------- RMS norm of x with scale = (cond@w_cond + 1) -----------------------
__global__ __launch_bounds__(256) void rmsnorm_x(const void* __restrict__ x,
                                                 const float* __restrict__ scl,
                                                 u16* __restrict__ xn,
                                                 const int* __restrict__ flag) {
    const int isf32 = *flag;
    const int tok = blockIdx.x;
    const int n = tok >> 11;
    u16* orow = xn + (size_t)tok * 1024;
    const int base = threadIdx.x * 4;
    float f0, f1, f2, f3;
    if (isf32) {
        const float4 v = *(const float4*)((const float*)x + (size_t)tok * 1024 + base);
        f0 = v.x; f1 = v.y; f2 = v.z; f3 = v.w;
    } else {
        s16x4 uv = *(const s16x4*)((const u16*)x + (size_t)tok * 1024 + base);
        f0 = bf2f((u16)uv[0]); f1 = bf2f((u16)uv[1]); f2 = bf2f((u16)uv[2]); f3 = bf2f((u16)uv[3]);
    }
    float ss = f0 * f0 + f1 * f1 + f2 * f2 + f3 * f3;
    #pragma unroll
    for (int m = 1; m < 64; m <<= 1) ss += __shfl_xor(ss, m, 64);
    __shared__ float red[4];
    const int wave = threadIdx.x >> 6, lane = threadIdx.x & 63;
    if (lane == 0) red[wave] = ss;
    __syncthreads();
    float ms = (red[0] + red[1] + red[2] + red[3]) * (1.f / 1024.f);
    float rinv = rsqrtf(ms + 1e-6f);
    orow[base + 0] = f2bf(f0 * (scl[n * 1024 + base + 0] + 1.f) * rinv);
    orow[base + 1] = f2bf(f1 * (scl[n * 1024 + base + 1] + 1.f) * rinv);
    orow[base + 2] = f2bf(f2 * (scl[n * 1024 + base + 2] + 1.f) * rinv);
    orow[base + 3] = f2bf(f3 * (scl[n * 1024 + base + 3] + 1.f) * rinv);
}

// ---------------- transpose (src R x C -> dst C x R), dual-dtype read, bf16 out ------
__global__ __launch_bounds__(256) void transpose_bf(const void* __restrict__ src,
                                                    u16* __restrict__ dst, int R, int C,
                                                    const int* __restrict__ flag) {
    const int isf32 = *flag;
    __shared__ u16 t[32][33];
    const int c0 = blockIdx.x * 32, r0 = blockIdx.y * 32;
    const int tx = threadIdx.x & 31, ty = threadIdx.x >> 5;
    #pragma unroll
    for (int i = 0; i < 4; ++i)
        t[ty + i * 8][tx] = f2bf(loadIn(src, (size_t)(r0 + ty + i * 8) * C + c0 + tx, isf32));
    __syncthreads();
    #pragma unroll
    for (int i = 0; i < 4; ++i)
        dst[(size_t)(c0 + ty + i * 8) * R + r0 + tx] = t[tx][ty + i * 8];
}

// ---------------- bf16 GEMM: C[M,N] = A[M,K] * BT[N,K]^T, 128x128 tile, BK=32 --------
template <typename OutT>
__global__ __launch_bounds__(256) void gemm_bt(const u16* __restrict__ A,
                                               const u16* __restrict__ BT,
                                               OutT* __restrict__ C, int Nn, int K) {
    __shared__ u16 As[128 * 32];
    __shared__ u16 Bs[128 * 32];
    const int tid = threadIdx.x;
    const int wave = tid >> 6, lane = tid & 63;
    const int l15 = lane & 15, quad = lane >> 4;
    const int bm0 = blockIdx.y * 128, bn0 = blockIdx.x * 128;
    const int wr = wave >> 1, wc = wave & 1;
    f32x4 acc[4][4] = {};
    const int srow = lane >> 2;
    const int g = (lane & 3) ^ (srow & 3);
    for (int bk = 0; bk < K; bk += 32) {
        __syncthreads();
        #pragma unroll
        for (int p = 0; p < 2; ++p) {
            const int rowl = p * 64 + wave * 16 + srow;
            const u16* ga = A + (size_t)(bm0 + rowl) * K + bk + g * 8;
            u16* la = As + (p * 64 + wave * 16) * 32;
            __builtin_amdgcn_global_load_lds((const AS1 void*)ga, (AS3 void*)la, 16, 0, 0);
            const u16* gb = BT + (size_t)(bn0 + rowl) * K + bk + g * 8;
            u16* lb = Bs + (p * 64 + wave * 16) * 32;
            __builtin_amdgcn_global_load_lds((const AS1 void*)gb, (AS3 void*)lb, 16, 0, 0);
        }
        __syncthreads();
        s16x8 af[4], bfr[4];
        #pragma unroll
        for (int mt = 0; mt < 4; ++mt) {
            const int r = wr * 64 + mt * 16 + l15;
            af[mt] = *(const s16x8*)(As + r * 32 + ((quad ^ (r & 3)) << 3));
        }
        #pragma unroll
        for (int nt = 0; nt < 4; ++nt) {
            const int r = wc * 64 + nt * 16 + l15;
            bfr[nt] = *(const s16x8*)(Bs + r * 32 + ((quad ^ (r & 3)) << 3));
        }
        #pragma unroll
        for (int mt = 0; mt < 4; ++mt)
            #pragma unroll
            for (int nt = 0; nt < 4; ++nt)
                acc[mt][nt] = __builtin_amdgcn_mfma_f32_16x16x32_bf16(af[mt], bfr[nt], acc[mt][nt], 0, 0, 0);
    }
    #pragma unroll
    for (int mt = 0; mt < 4; ++mt)
        #pragma unroll
        for (int nt = 0; nt < 4; ++nt)
            #pragma unroll
            for (int r = 0; r < 4; ++r) {
                const int row = bm0 + wr * 64 + mt * 16 + quad * 4 + r;
                const int col = bn0 + wc * 64 + nt * 16 + l15;
                storeOut(C + (size_t)row * Nn + col, acc[mt][nt][r]);
            }
}

// ---------------- fused per-head q/k RMS+RoPE + V transpose --------------------------
// grid (32 l-tiles, 32 nh), 256 thr. Wave handles 16 tokens (one per iter, lane = e).
// q scaled by s^2/8 * log2(e) so attention softmax uses exp2 with fixed shift.
__global__ __launch_bounds__(256) void qkv_head(const u16* __restrict__ qkv,
                                                const void* __restrict__ pos,
                                                const void* __restrict__ qk_scale,
                                                u16* __restrict__ q_ws,
                                                u16* __restrict__ k_ws,
                                                u16* __restrict__ vtg,
                                                const int* __restrict__ flag) {
    const int isf32 = *flag;
    const int nh = blockIdx.y;
    const int n = nh >> 4, h = nh & 15;
    const int l0 = blockIdx.x * 64;
    const int tid = threadIdx.x;
    const int wave = tid >> 6, lane = tid & 63;

    // per-lane constants (hoisted out of the token loop)
    const float qs = loadIn(qk_scale, h, isf32);
    const float s = __expf(0.5f * fminf(qs, 4.605170186f) - 1.039720771f);
    const float qmul = s * s * 0.125f * 1.44269504089f;
    const int j = lane & 31;
    const float t = (float)((j & 15) * 16 + h);
    const float freq = 3.14159265358979f * __expf(t * (2.302585093f / 256.f));
    const int pj = j >> 4;

    #pragma unroll 2
    for (int it = 0; it < 16; ++it) {
        const int l = l0 + wave * 16 + it;
        const int tok = n * 2048 + l;
        const u16* row = qkv + (size_t)tok * 3072;
        float qv = bf2f(row[h * 64 + lane]);
        float kv = bf2f(row[1024 + h * 64 + lane]);
        float q2 = qv * qv, k2 = kv * kv;
        #pragma unroll
        for (int m = 1; m < 64; m <<= 1) { q2 += __shfl_xor(q2, m, 64); k2 += __shfl_xor(k2, m, 64); }
        float qn = qv * rsqrtf(q2 * (1.f / 64.f) + 1e-6f) * qmul;
        float kn = kv * rsqrtf(k2 * (1.f / 64.f) + 1e-6f);
        const float p = loadIn(pos, tok * 2 + pj, isf32);
        const float th = p * freq;
        const float c = __cosf(th), sn = __sinf(th);
        const float pq = __shfl_xor(qn, 32, 64);
        const float pk = __shfl_xor(kn, 32, 64);
        float qr, kr;
        if (lane < 32) { qr = qn * c - pq * sn; kr = kn * c - pk * sn; }
        else           { qr = qn * c + pq * sn; kr = kn * c + pk * sn; }
        const size_t oidx = ((size_t)nh * 2048 + l) * 64 + lane;
        q_ws[oidx] = f2bf(qr);
        k_ws[oidx] = f2bf(kr);
    }

    // V transpose: 64 l x 64 e tile -> vtg[nh][e][l]
    __shared__ u16 tbuf[64][65];
    const u16* vsrc = qkv + (size_t)(n * 2048 + l0) * 3072 + 2048 + h * 64;
    #pragma unroll
    for (int it = 0; it < 16; ++it) {
        const int idx = it * 256 + tid;
        const int r = idx >> 6, c = idx & 63;
        tbuf[r][c] = vsrc[(size_t)r * 3072 + c];
    }
    __syncthreads();
    u16* dst = vtg + (size_t)nh * 131072 + l0;
    #pragma unroll
    for (int it = 0; it < 16; ++it) {
        const int idx = it * 256 + tid;
        const int er = idx >> 6, lc = idx & 63;
        dst[(size_t)er * 2048 + lc] = tbuf[lc][er];
    }
}

// ---------------- flash attention v8: 32x32 MFMA, in-register P, counted vmcnt -------
// 256 thr (4 waves), 32 q/wave, q-tile 128, k-tile 64, 32 iters.
// attn6 post-mortem: LDS-port-bound (~144 KB LDS reads per 128q-iter at 16q/wave).
// (a) 32q/wave halves K/V fragment reads per q-row; (b) QK and PV use
// mfma_f32_32x32x16_bf16 with P kept IN REGISTERS: S^T D-layout (col=lane&31=q,
// row=(r&3)+8*(r>>2)+4*(lane>>5)) -> PV A-layout via 8 v_cvt_pk_bf16_f32 +
// 4 v_permlane32_swap_b32 (after swap(c0,c2),swap(c1,c3): half h=0 holds k0..7,
// h=1 holds k8..15 = exact A-operand rows; likewise c4..c7 for k16..31);
// (c) K/V triple-buffered, prefetch 2 tiles ahead, counted s_waitcnt vmcnt(4) +
// sched_barrier + raw s_barrier (m201 pattern) -- never drains to 0 in-loop.
// LDS = 48 KB (no P buffer). QK acc init -15 = softmax shift folded into exp2.
__global__ __launch_bounds__(256, 2) void attn8(const u16* __restrict__ Q,
                                                const u16* __restrict__ K,
                                                const u16* __restrict__ Vtg,
                                                u16* __restrict__ O) {
    __shared__ u16 Ks[3][64 * 64];
    __shared__ u16 Vt[3][64 * 64];
    const int nh = blockIdx.y;
    const int q0 = blockIdx.x * 128;
    const int tid = threadIdx.x;
    const int wave = tid >> 6, lane = tid & 63;
    const int l31 = lane & 31, h = lane >> 5;
    const size_t hb = (size_t)nh * 2048 * 64;
    const u16* Vbase = Vtg + (size_t)nh * 131072;
    const int drow = lane >> 3;          // row within 8-row DMA chunk
    const int dch = lane & 7;            // 16B chunk within 128B row

    // Q fragments (B-operand of 32x32x16: col=q=l31, rows e=kd*16+h*8+0..7)
    s16x8 qf[4];
    #pragma unroll
    for (int kd = 0; kd < 4; ++kd)
        qf[kd] = *(const s16x8*)(Q + hb + (size_t)(q0 + wave * 32 + l31) * 64 + kd * 16 + h * 8);

    f32x16 Oacc[2] = {};
    float lacc = 0.f;

    // stage K-tile rows [wave*16, wave*16+16) and V^T rows likewise: 4 loads/wave/tile
    auto stage = [&](int tile, int slot) {
        const int kb = tile * 64;
        #pragma unroll
        for (int inst = 0; inst < 2; ++inst) {
            const int row = wave * 16 + inst * 8 + drow;
            const int g = dch ^ (row & 7);
            __builtin_amdgcn_global_load_lds(
                (const AS1 void*)(K + hb + (size_t)(kb + row) * 64 + g * 8),
                (AS3 void*)(Ks[slot] + (wave * 16 + inst * 8) * 64), 16, 0, 0);
            __builtin_amdgcn_global_load_lds(
                (const AS1 void*)(Vbase + (size_t)row * 2048 + kb + g * 8),
                (AS3 void*)(Vt[slot] + (wave * 16 + inst * 8) * 64), 16, 0, 0);
        }
    };

    stage(0, 0);
    stage(1, 1);
    int s0 = 0, s1 = 1, s2 = 2;

    for (int i = 0; i < 32; ++i) {
        // wait for all but the newest 4 loads (tile i+1) -> this wave's tile-i rows in.
        asm volatile("s_waitcnt vmcnt(4)" ::: "memory");
        __builtin_amdgcn_sched_barrier(0);
        // barrier: all waves have their tile-i rows in AND finished reading tile i-1.
        __builtin_amdgcn_s_barrier();
        // prefetch tile i+2 into the slot that held tile i-1 (clamped dummy at tail
        // keeps the vmcnt arithmetic exact)
        stage(i < 30 ? i + 2 : 31, s2);

        const u16* Kt = Ks[s0];
        const u16* Vc = Vt[s0];

        #pragma unroll
        for (int kt = 0; kt < 2; ++kt) {
            // ---- QK: S^T(32k x 32q) = K-half * Q^T, contraction e=64 in 4 steps ----
            f32x16 S;
            #pragma unroll
            for (int jj = 0; jj < 16; ++jj) S[jj] = -15.f;
            const int kr = kt * 32 + l31;
            #pragma unroll
            for (int kd = 0; kd < 4; ++kd) {
                const s16x8 kf = *(const s16x8*)(Kt + kr * 64 + ((((kd << 1) + h) ^ (kr & 7)) << 3));
                S = __builtin_amdgcn_mfma_f32_32x32x16_bf16(kf, qf[kd], S, 0, 0, 0);
            }
            // ---- softmax: exp2 (shift -15 in acc init), row-sum partial ----
            float e[16];
            #pragma unroll
            for (int jj = 0; jj < 16; ++jj) e[jj] = fexp2(S[jj]);
            float rs = 0.f;
            #pragma unroll
            for (int jj = 0; jj < 16; ++jj) rs += e[jj];
            lacc += rs;
            // ---- pack P to bf16 pairs + half-swap into PV A-fragments ----
            u32 c[8];
            #pragma unroll
            for (int jj = 0; jj < 8; ++jj)
                asm("v_cvt_pk_bf16_f32 %0, %1, %2" : "=v"(c[jj]) : "v"(e[2 * jj]), "v"(e[2 * jj + 1]));
            plswap(c[0], c[2]);
            plswap(c[1], c[3]);
            plswap(c[4], c[6]);
            plswap(c[5], c[7]);
            union { u32 u[4]; s16x8 v; } pfa, pfb;
            pfa.u[0] = c[0]; pfa.u[1] = c[1]; pfa.u[2] = c[2]; pfa.u[3] = c[3];
            pfb.u[0] = c[4]; pfb.u[1] = c[5]; pfb.u[2] = c[6]; pfb.u[3] = c[7];
            // ---- PV: Oacc(32q x 32e per et) += P(32q x 32k) * V(32k x 32e) ----
            #pragma unroll
            for (int et = 0; et < 2; ++et) {
                const int er = et * 32 + l31;
                #pragma unroll
                for (int kdp = 0; kdp < 2; ++kdp) {
                    const int ch = kt * 4 + kdp * 2 + h;
                    const s16x8 vf = *(const s16x8*)(Vc + er * 64 + ((ch ^ (er & 7)) << 3));
                    Oacc[et] = __builtin_amdgcn_mfma_f32_32x32x16_bf16(kdp ? pfb.v : pfa.v, vf, Oacc[et], 0, 0, 0);
                }
            }
        }
        const int t = s0; s0 = s1; s1 = s2; s2 = t;
    }
    // drain dummy tail prefetches before epilogue
    asm volatile("s_waitcnt vmcnt(0)" ::: "memory");

    // ---- epilogue: combine row-sums across lane halves, normalize, store ----
    lacc += __shfl_xor(lacc, 32, 64);
    const float linv_l = 1.f / lacc;   // lane l31 holds 1/l for q = l31
    const int n = nh >> 4, hh = nh & 15;
    #pragma unroll
    for (int r = 0; r < 16; ++r) {
        const int ql = (r & 3) + 8 * (r >> 2) + 4 * h;   // q-row of D-reg r
        const float linv = __shfl(linv_l, ql, 64);
        const int qrow = q0 + wave * 32 + ql;
        #pragma unroll
        for (int et = 0; et < 2; ++et)
            O[((size_t)n * 2048 + qrow) * 1024 + hh * 64 + et * 32 + l31] = f2bf(Oacc[et][r] * linv);
    }
}

// ---------------- launch --------------------------------------------------------------
extern "C" void kernel_launch(void* const* d_in, const int* in_sizes, int n_in,
                              void* d_out, int out_size, void* d_ws, size_t ws_size,
                              hipStream_t stream) {
    const void* x        = d_in[0];
    const void* pos      = d_in[1];
    const void* cond     = d_in[2];
    const void* w_cond   = d_in[3];
    const void* w_qkv    = d_in[4];
    const void* qk_scale = d_in[5];
    const void* w_out    = d_in[6];

    char* ws = (char*)d_ws;
    constexpr size_t OFS_SCALE = 0;
    constexpr size_t OFS_FLAG  = 8192;
    constexpr size_t OFS_XN    = 16384;
    constexpr size_t OFS_WQKVT = OFS_XN    + 8388608;
    constexpr size_t OFS_WOUTT = OFS_WQKVT + 6291456;
    constexpr size_t OFS_QKV   = OFS_WOUTT + 2097152;
    constexpr size_t OFS_Q     = OFS_QKV   + 25165824;
    constexpr size_t OFS_K     = OFS_Q     + 8388608;
    constexpr size_t OFS_VT    = OFS_K     + 8388608;
    constexpr size_t OFS_O     = OFS_VT    + 8388608;

    float* scale = (float*)(ws + OFS_SCALE);
    int*   flag  = (int*)(ws + OFS_FLAG);
    u16* xn    = (u16*)(ws + OFS_XN);
    u16* wqkvT = (u16*)(ws + OFS_WQKVT);
    u16* woutT = (u16*)(ws + OFS_WOUTT);
    u16* qkv   = (u16*)(ws + OFS_QKV);
    u16* qws   = (u16*)(ws + OFS_Q);
    u16* kws   = (u16*)(ws + OFS_K);
    u16* vtg   = (u16*)(ws + OFS_VT);
    u16* ows   = (u16*)(ws + OFS_O);

    detect_dtype<<<dim3(1), 256, 0, stream>>>((const u16*)x, flag);
    hipMemsetAsync(scale, 0, 2 * 1024 * sizeof(float), stream);
    cond_gemv<<<dim3(4, 2, 16), 256, 0, stream>>>(cond, w_cond, scale, flag);
    rmsnorm_x<<<dim3(4096), 256, 0, stream>>>(x, scale, xn, flag);
    transpose_bf<<<dim3(96, 32), 256, 0, stream>>>(w_qkv, wqkvT, 1024, 3072, flag);
    transpose_bf<<<dim3(32, 32), 256, 0, stream>>>(w_out, woutT, 1024, 1024, flag);
    gemm_bt<u16><<<dim3(24, 32), 256, 0, stream>>>(xn, wqkvT, qkv, 3072, 1024);
    qkv_head<<<dim3(32, 32), 256, 0, stream>>>(qkv, pos, qk_scale, qws, kws, vtg, flag);
    attn8<<<dim3(16, 32), 256, 0, stream>>>(qws, kws, vtg, ows);
    gemm_bt<float><<<dim3(8, 32), 256, 0, stream>>>(ows, woutT, (float*)d_out, 1024, 1024);
}

// Round 4
// 230.251 us; speedup vs baseline: 1.0458x; 1.0058x over previous
//
#include <hip/hip_runtime.h>

typedef unsigned short u16;
typedef unsigned int u32;
typedef short s16x8 __attribute__((ext_vector_type(8)));
typedef short s16x4 __attribute__((ext_vector_type(4)));
typedef float f32x4 __attribute__((ext_vector_type(4)));
typedef float f32x16 __attribute__((ext_vector_type(16)));

#define AS1 __attribute__((address_space(1)))
#define AS3 __attribute__((address_space(3)))

__device__ __forceinline__ float bf2f(u16 u) {
    union { unsigned int i; float f; } x; x.i = ((unsigned int)u) << 16; return x.f;
}
__device__ __forceinline__ u16 f2bf(float f) {
    union { float f; unsigned int i; } x; x.f = f;
    unsigned int r = (x.i + 0x7FFFu + ((x.i >> 16) & 1u)) >> 16;
    return (u16)r;
}
__device__ __forceinline__ void storeOut(u16* p, float v) { *p = f2bf(v); }
__device__ __forceinline__ void storeOut(float* p, float v) { *p = v; }
__device__ __forceinline__ float loadIn(const void* p, size_t i, int isf32) {
    return isf32 ? ((const float*)p)[i] : bf2f(((const u16*)p)[i]);
}
__device__ __forceinline__ float fexp2(float x) {
#if __has_builtin(__builtin_amdgcn_exp2f)
    return __builtin_amdgcn_exp2f(x);
#else
    return exp2f(x);
#endif
}
// exchange upper half-lanes of a with lower half-lanes of b (v_permlane32_swap_b32)
__device__ __forceinline__ void plswap(u32& a, u32& b) {
#if __has_builtin(__builtin_amdgcn_permlane32_swap)
    const auto r = __builtin_amdgcn_permlane32_swap(a, b, false, false);
    a = (u32)r[0]; b = (u32)r[1];
#else
    asm("v_permlane32_swap_b32 %0, %1" : "+v"(a), "+v"(b));
#endif
}

// ---------------- runtime dtype detector ---------------------------------------------
__global__ __launch_bounds__(256) void detect_dtype(const u16* __restrict__ x,
                                                    int* __restrict__ flag) {
    __shared__ int cnt[4];
    const int tid = threadIdx.x;
    int c = 0;
    #pragma unroll
    for (int i = 0; i < 4; ++i) {
        const u16 u = x[tid * 4 + i];
        const int e = (u >> 7) & 0xFF;
        c += (e >= 101 && e <= 135) ? 1 : 0;
    }
    #pragma unroll
    for (int m = 1; m < 64; m <<= 1) c += __shfl_xor(c, m, 64);
    if ((tid & 63) == 0) cnt[tid >> 6] = c;
    __syncthreads();
    if (tid == 0) {
        const int t = cnt[0] + cnt[1] + cnt[2] + cnt[3];
        *flag = (t < 800) ? 1 : 0;   // 1 = inputs are float32
    }
}

// ---------------- cond @ w_cond (split-K GEMV, atomicAdd into zeroed f32 ws) ----------
__global__ __launch_bounds__(256) void cond_gemv(const void* __restrict__ cond,
                                                 const void* __restrict__ w,
                                                 float* __restrict__ out,
                                                 const int* __restrict__ flag) {
    const int isf32 = *flag;
    const int d  = blockIdx.x * 256 + threadIdx.x;
    const int n  = blockIdx.y;
    const int k0 = blockIdx.z * 64;
    float acc = 0.f;
    #pragma unroll 8
    for (int k = 0; k < 64; ++k)
        acc += loadIn(cond, n * 1024 + k0 + k, isf32) *
               loadIn(w, (size_t)(k0 + k) * 1024 + d, isf32);
    atomicAdd(out + n * 1024 + d, acc);
}

// ---------------- RMS norm of x with scale = (cond@w_cond + 1) -----------------------
__global__ __launch_bounds__(256) void rmsnorm_x(const void* __restrict__ x,
                                                 const float* __restrict__ scl,
                                                 u16* __restrict__ xn,
                                                 const int* __restrict__ flag) {
    const int isf32 = *flag;
    const int tok = blockIdx.x;
    const int n = tok >> 11;
    u16* orow = xn + (size_t)tok * 1024;
    const int base = threadIdx.x * 4;
    float f0, f1, f2, f3;
    if (isf32) {
        const float4 v = *(const float4*)((const float*)x + (size_t)tok * 1024 + base);
        f0 = v.x; f1 = v.y; f2 = v.z; f3 = v.w;
    } else {
        s16x4 uv = *(const s16x4*)((const u16*)x + (size_t)tok * 1024 + base);
        f0 = bf2f((u16)uv[0]); f1 = bf2f((u16)uv[1]); f2 = bf2f((u16)uv[2]); f3 = bf2f((u16)uv[3]);
    }
    float ss = f0 * f0 + f1 * f1 + f2 * f2 + f3 * f3;
    #pragma unroll
    for (int m = 1; m < 64; m <<= 1) ss += __shfl_xor(ss, m, 64);
    __shared__ float red[4];
    const int wave = threadIdx.x >> 6, lane = threadIdx.x & 63;
    if (lane == 0) red[wave] = ss;
    __syncthreads();
    float ms = (red[0] + red[1] + red[2] + red[3]) * (1.f / 1024.f);
    float rinv = rsqrtf(ms + 1e-6f);
    orow[base + 0] = f2bf(f0 * (scl[n * 1024 + base + 0] + 1.f) * rinv);
    orow[base + 1] = f2bf(f1 * (scl[n * 1024 + base + 1] + 1.f) * rinv);
    orow[base + 2] = f2bf(f2 * (scl[n * 1024 + base + 2] + 1.f) * rinv);
    orow[base + 3] = f2bf(f3 * (scl[n * 1024 + base + 3] + 1.f) * rinv);
}

// ---------------- transpose (src R x C -> dst C x R), dual-dtype read, bf16 out ------
__global__ __launch_bounds__(256) void transpose_bf(const void* __restrict__ src,
                                                    u16* __restrict__ dst, int R, int C,
                                                    const int* __restrict__ flag) {
    const int isf32 = *flag;
    __shared__ u16 t[32][33];
    const int c0 = blockIdx.x * 32, r0 = blockIdx.y * 32;
    const int tx = threadIdx.x & 31, ty = threadIdx.x >> 5;
    #pragma unroll
    for (int i = 0; i < 4; ++i)
        t[ty + i * 8][tx] = f2bf(loadIn(src, (size_t)(r0 + ty + i * 8) * C + c0 + tx, isf32));
    __syncthreads();
    #pragma unroll
    for (int i = 0; i < 4; ++i)
        dst[(size_t)(c0 + ty + i * 8) * R + r0 + tx] = t[tx][ty + i * 8];
}

// ---------------- bf16 GEMM: C[M,N] = A[M,K] * BT[N,K]^T, 128x128 tile, BK=32 --------
template <typename OutT>
__global__ __launch_bounds__(256) void gemm_bt(const u16* __restrict__ A,
                                               const u16* __restrict__ BT,
                                               OutT* __restrict__ C, int Nn, int K) {
    __shared__ u16 As[128 * 32];
    __shared__ u16 Bs[128 * 32];
    const int tid = threadIdx.x;
    const int wave = tid >> 6, lane = tid & 63;
    const int l15 = lane & 15, quad = lane >> 4;
    const int bm0 = blockIdx.y * 128, bn0 = blockIdx.x * 128;
    const int wr = wave >> 1, wc = wave & 1;
    f32x4 acc[4][4] = {};
    const int srow = lane >> 2;
    const int g = (lane & 3) ^ (srow & 3);
    for (int bk = 0; bk < K; bk += 32) {
        __syncthreads();
        #pragma unroll
        for (int p = 0; p < 2; ++p) {
            const int rowl = p * 64 + wave * 16 + srow;
            const u16* ga = A + (size_t)(bm0 + rowl) * K + bk + g * 8;
            u16* la = As + (p * 64 + wave * 16) * 32;
            __builtin_amdgcn_global_load_lds((const AS1 void*)ga, (AS3 void*)la, 16, 0, 0);
            const u16* gb = BT + (size_t)(bn0 + rowl) * K + bk + g * 8;
            u16* lb = Bs + (p * 64 + wave * 16) * 32;
            __builtin_amdgcn_global_load_lds((const AS1 void*)gb, (AS3 void*)lb, 16, 0, 0);
        }
        __syncthreads();
        s16x8 af[4], bfr[4];
        #pragma unroll
        for (int mt = 0; mt < 4; ++mt) {
            const int r = wr * 64 + mt * 16 + l15;
            af[mt] = *(const s16x8*)(As + r * 32 + ((quad ^ (r & 3)) << 3));
        }
        #pragma unroll
        for (int nt = 0; nt < 4; ++nt) {
            const int r = wc * 64 + nt * 16 + l15;
            bfr[nt] = *(const s16x8*)(Bs + r * 32 + ((quad ^ (r & 3)) << 3));
        }
        #pragma unroll
        for (int mt = 0; mt < 4; ++mt)
            #pragma unroll
            for (int nt = 0; nt < 4; ++nt)
                acc[mt][nt] = __builtin_amdgcn_mfma_f32_16x16x32_bf16(af[mt], bfr[nt], acc[mt][nt], 0, 0, 0);
    }
    #pragma unroll
    for (int mt = 0; mt < 4; ++mt)
        #pragma unroll
        for (int nt = 0; nt < 4; ++nt)
            #pragma unroll
            for (int r = 0; r < 4; ++r) {
                const int row = bm0 + wr * 64 + mt * 16 + quad * 4 + r;
                const int col = bn0 + wc * 64 + nt * 16 + l15;
                storeOut(C + (size_t)row * Nn + col, acc[mt][nt][r]);
            }
}

// ---------------- fused per-head q/k RMS+RoPE + V transpose --------------------------
// grid (32 l-tiles, 32 nh), 256 thr. Wave handles 16 tokens (one per iter, lane = e).
// q scaled by s^2/8 * log2(e) so attention softmax uses exp2 with fixed shift.
__global__ __launch_bounds__(256) void qkv_head(const u16* __restrict__ qkv,
                                                const void* __restrict__ pos,
                                                const void* __restrict__ qk_scale,
                                                u16* __restrict__ q_ws,
                                                u16* __restrict__ k_ws,
                                                u16* __restrict__ vtg,
                                                const int* __restrict__ flag) {
    const int isf32 = *flag;
    const int nh = blockIdx.y;
    const int n = nh >> 4, h = nh & 15;
    const int l0 = blockIdx.x * 64;
    const int tid = threadIdx.x;
    const int wave = tid >> 6, lane = tid & 63;

    // per-lane constants (hoisted out of the token loop)
    const float qs = loadIn(qk_scale, h, isf32);
    const float s = __expf(0.5f * fminf(qs, 4.605170186f) - 1.039720771f);
    const float qmul = s * s * 0.125f * 1.44269504089f;
    const int j = lane & 31;
    const float t = (float)((j & 15) * 16 + h);
    const float freq = 3.14159265358979f * __expf(t * (2.302585093f / 256.f));
    const int pj = j >> 4;

    #pragma unroll 2
    for (int it = 0; it < 16; ++it) {
        const int l = l0 + wave * 16 + it;
        const int tok = n * 2048 + l;
        const u16* row = qkv + (size_t)tok * 3072;
        float qv = bf2f(row[h * 64 + lane]);
        float kv = bf2f(row[1024 + h * 64 + lane]);
        float q2 = qv * qv, k2 = kv * kv;
        #pragma unroll
        for (int m = 1; m < 64; m <<= 1) { q2 += __shfl_xor(q2, m, 64); k2 += __shfl_xor(k2, m, 64); }
        float qn = qv * rsqrtf(q2 * (1.f / 64.f) + 1e-6f) * qmul;
        float kn = kv * rsqrtf(k2 * (1.f / 64.f) + 1e-6f);
        const float p = loadIn(pos, tok * 2 + pj, isf32);
        const float th = p * freq;
        const float c = __cosf(th), sn = __sinf(th);
        const float pq = __shfl_xor(qn, 32, 64);
        const float pk = __shfl_xor(kn, 32, 64);
        float qr, kr;
        if (lane < 32) { qr = qn * c - pq * sn; kr = kn * c - pk * sn; }
        else           { qr = qn * c + pq * sn; kr = kn * c + pk * sn; }
        const size_t oidx = ((size_t)nh * 2048 + l) * 64 + lane;
        q_ws[oidx] = f2bf(qr);
        k_ws[oidx] = f2bf(kr);
    }

    // V transpose: 64 l x 64 e tile -> vtg[nh][e][l]
    __shared__ u16 tbuf[64][65];
    const u16* vsrc = qkv + (size_t)(n * 2048 + l0) * 3072 + 2048 + h * 64;
    #pragma unroll
    for (int it = 0; it < 16; ++it) {
        const int idx = it * 256 + tid;
        const int r = idx >> 6, c = idx & 63;
        tbuf[r][c] = vsrc[(size_t)r * 3072 + c];
    }
    __syncthreads();
    u16* dst = vtg + (size_t)nh * 131072 + l0;
    #pragma unroll
    for (int it = 0; it < 16; ++it) {
        const int idx = it * 256 + tid;
        const int er = idx >> 6, lc = idx & 63;
        dst[(size_t)er * 2048 + lc] = tbuf[lc][er];
    }
}

// ---------------- flash attention v9: q-tile 256, 256-key chunks, 128 KB LDS ---------
// 512 thr (8 waves x 32q), grid (8, 32) = 256 blocks = 1/CU. kv iterated in 8 chunks
// of 256 keys, double-buffered (2 x (K 32K + V 32K) = 128 KB LDS).
// Round-3 post-mortem: attn5/6/8 (3 different schedules) all ~55 us -> the shared
// invariant was 512 blocks x 32 barrier-bracketed 16 KB staging steps (256 MB total
// staged, 70 MB HBM fetch). This version halves staged bytes (q-tile 256 -> 256
// blocks) and cuts barriers 4x (2 per 256-key chunk, 16 total). Inner kt body is
// attn8's proven 32x32-MFMA in-register-P pipeline, 8 kt per chunk between syncs.
// QK acc init -15 = softmax shift folded into exp2 (q pre-scaled by s^2/8*log2e).
__global__ __launch_bounds__(512, 2) void attn9(const u16* __restrict__ Q,
                                                const u16* __restrict__ K,
                                                const u16* __restrict__ Vtg,
                                                u16* __restrict__ O) {
    __shared__ u16 Ks[2][256 * 64];   // chunk rows x 64 e (128 B rows)
    __shared__ u16 Vt[2][64 * 256];   // 64 e-rows x chunk cols (512 B rows)
    const int nh = blockIdx.y;
    const int q0 = blockIdx.x * 256;
    const int tid = threadIdx.x;
    const int wave = tid >> 6, lane = tid & 63;
    const int l31 = lane & 31, h = lane >> 5;
    const size_t hb = (size_t)nh * 2048 * 64;
    const u16* Vbase = Vtg + (size_t)nh * 131072;

    // Q fragments (B-operand of 32x32x16: col=q=l31, rows e=kd*16+h*8+0..7)
    s16x8 qf[4];
    #pragma unroll
    for (int kd = 0; kd < 4; ++kd)
        qf[kd] = *(const s16x8*)(Q + hb + (size_t)(q0 + wave * 32 + l31) * 64 + kd * 16 + h * 8);

    f32x16 Oacc[2] = {};
    float lacc = 0.f;

    // stage one 256-key chunk: K 32 KB (4 rounds of 64 rows) + V 32 KB (4 rounds of
    // 16 e-rows). 8 global_load_lds per wave per chunk, LDS dest linear, source
    // pre-swizzled so frag reads can XOR-deswizzle (bank spread).
    auto stage = [&](int ch, int slot) {
        const int kb = ch * 256;
        #pragma unroll
        for (int r = 0; r < 4; ++r) {
            const int row = r * 64 + wave * 8 + (lane >> 3);
            const int g = (lane & 7) ^ (row & 7);
            __builtin_amdgcn_global_load_lds(
                (const AS1 void*)(K + hb + (size_t)(kb + row) * 64 + g * 8),
                (AS3 void*)(Ks[slot] + (r * 64 + wave * 8) * 64), 16, 0, 0);
        }
        #pragma unroll
        for (int r = 0; r < 4; ++r) {
            const int er = (r * 8 + wave) * 2 + (lane >> 5);
            const int g2 = (lane & 31) ^ (er & 7);
            __builtin_amdgcn_global_load_lds(
                (const AS1 void*)(Vbase + (size_t)er * 2048 + kb + g2 * 8),
                (AS3 void*)(Vt[slot] + (r * 8 + wave) * 2 * 256), 16, 0, 0);
        }
    };

    stage(0, 0);

    for (int j = 0; j < 8; ++j) {
        // top barrier: all waves finished reading buf[(j+1)&1] (used by chunk j-1)
        if (j > 0) __builtin_amdgcn_s_barrier();
        if (j < 7) {
            stage(j + 1, (j + 1) & 1);
            // wait for chunk j's 8 loads (oldest); 8 newest (chunk j+1) stay in flight
            asm volatile("s_waitcnt vmcnt(8)" ::: "memory");
        } else {
            asm volatile("s_waitcnt vmcnt(0)" ::: "memory");
        }
        __builtin_amdgcn_sched_barrier(0);
        __builtin_amdgcn_s_barrier();   // all waves' chunk-j rows present in LDS

        const u16* Kt = Ks[j & 1];
        const u16* Vc = Vt[j & 1];

        #pragma unroll 2
        for (int kt = 0; kt < 8; ++kt) {
            // ---- QK: S^T(32k x 32q) = K-slice * Q^T, contraction e=64 in 4 steps ----
            f32x16 S;
            #pragma unroll
            for (int jj = 0; jj < 16; ++jj) S[jj] = -15.f;
            const int kr = kt * 32 + l31;
            #pragma unroll
            for (int kd = 0; kd < 4; ++kd) {
                const s16x8 kf = *(const s16x8*)(Kt + kr * 64 + ((((kd << 1) + h) ^ (kr & 7)) << 3));
                S = __builtin_amdgcn_mfma_f32_32x32x16_bf16(kf, qf[kd], S, 0, 0, 0);
            }
            // ---- softmax: exp2 (shift -15 in acc init), row-sum partial ----
            float e[16];
            #pragma unroll
            for (int jj = 0; jj < 16; ++jj) e[jj] = fexp2(S[jj]);
            float rs = 0.f;
            #pragma unroll
            for (int jj = 0; jj < 16; ++jj) rs += e[jj];
            lacc += rs;
            // ---- pack P to bf16 pairs + half-swap into PV A-fragments ----
            u32 c[8];
            #pragma unroll
            for (int jj = 0; jj < 8; ++jj)
                asm("v_cvt_pk_bf16_f32 %0, %1, %2" : "=v"(c[jj]) : "v"(e[2 * jj]), "v"(e[2 * jj + 1]));
            plswap(c[0], c[2]);
            plswap(c[1], c[3]);
            plswap(c[4], c[6]);
            plswap(c[5], c[7]);
            union { u32 u[4]; s16x8 v; } pfa, pfb;
            pfa.u[0] = c[0]; pfa.u[1] = c[1]; pfa.u[2] = c[2]; pfa.u[3] = c[3];
            pfb.u[0] = c[4]; pfb.u[1] = c[5]; pfb.u[2] = c[6]; pfb.u[3] = c[7];
            // ---- PV: Oacc(32q x 32e per et) += P(32q x 32k) * V(32k x 32e) ----
            #pragma unroll
            for (int et = 0; et < 2; ++et) {
                const int er = et * 32 + l31;
                #pragma unroll
                for (int kdp = 0; kdp < 2; ++kdp) {
                    const int ch = kt * 4 + kdp * 2 + h;
                    const s16x8 vf = *(const s16x8*)(Vc + er * 256 + ((ch ^ (er & 7)) << 3));
                    Oacc[et] = __builtin_amdgcn_mfma_f32_32x32x16_bf16(kdp ? pfb.v : pfa.v, vf, Oacc[et], 0, 0, 0);
                }
            }
        }
    }

    // ---- epilogue: combine row-sums across lane halves, normalize, store ----
    lacc += __shfl_xor(lacc, 32, 64);
    const float linv_l = 1.f / lacc;   // lane l31 holds 1/l for q = l31
    const int n = nh >> 4, hh = nh & 15;
    #pragma unroll
    for (int r = 0; r < 16; ++r) {
        const int ql = (r & 3) + 8 * (r >> 2) + 4 * h;   // q-row of D-reg r
        const float linv = __shfl(linv_l, ql, 64);
        const int qrow = q0 + wave * 32 + ql;
        #pragma unroll
        for (int et = 0; et < 2; ++et)
            O[((size_t)n * 2048 + qrow) * 1024 + hh * 64 + et * 32 + l31] = f2bf(Oacc[et][r] * linv);
    }
}

// ---------------- launch --------------------------------------------------------------
extern "C" void kernel_launch(void* const* d_in, const int* in_sizes, int n_in,
                              void* d_out, int out_size, void* d_ws, size_t ws_size,
                              hipStream_t stream) {
    const void* x        = d_in[0];
    const void* pos      = d_in[1];
    const void* cond     = d_in[2];
    const void* w_cond   = d_in[3];
    const void* w_qkv    = d_in[4];
    const void* qk_scale = d_in[5];
    const void* w_out    = d_in[6];

    char* ws = (char*)d_ws;
    constexpr size_t OFS_SCALE = 0;
    constexpr size_t OFS_FLAG  = 8192;
    constexpr size_t OFS_XN    = 16384;
    constexpr size_t OFS_WQKVT = OFS_XN    + 8388608;
    constexpr size_t OFS_WOUTT = OFS_WQKVT + 6291456;
    constexpr size_t OFS_QKV   = OFS_WOUTT + 2097152;
    constexpr size_t OFS_Q     = OFS_QKV   + 25165824;
    constexpr size_t OFS_K     = OFS_Q     + 8388608;
    constexpr size_t OFS_VT    = OFS_K     + 8388608;
    constexpr size_t OFS_O     = OFS_VT    + 8388608;

    float* scale = (float*)(ws + OFS_SCALE);
    int*   flag  = (int*)(ws + OFS_FLAG);
    u16* xn    = (u16*)(ws + OFS_XN);
    u16* wqkvT = (u16*)(ws + OFS_WQKVT);
    u16* woutT = (u16*)(ws + OFS_WOUTT);
    u16* qkv   = (u16*)(ws + OFS_QKV);
    u16* qws   = (u16*)(ws + OFS_Q);
    u16* kws   = (u16*)(ws + OFS_K);
    u16* vtg   = (u16*)(ws + OFS_VT);
    u16* ows   = (u16*)(ws + OFS_O);

    detect_dtype<<<dim3(1), 256, 0, stream>>>((const u16*)x, flag);
    hipMemsetAsync(scale, 0, 2 * 1024 * sizeof(float), stream);
    cond_gemv<<<dim3(4, 2, 16), 256, 0, stream>>>(cond, w_cond, scale, flag);
    rmsnorm_x<<<dim3(4096), 256, 0, stream>>>(x, scale, xn, flag);
    transpose_bf<<<dim3(96, 32), 256, 0, stream>>>(w_qkv, wqkvT, 1024, 3072, flag);
    transpose_bf<<<dim3(32, 32), 256, 0, stream>>>(w_out, woutT, 1024, 1024, flag);
    gemm_bt<u16><<<dim3(24, 32), 256, 0, stream>>>(xn, wqkvT, qkv, 3072, 1024);
    qkv_head<<<dim3(32, 32), 256, 0, stream>>>(qkv, pos, qk_scale, qws, kws, vtg, flag);
    attn9<<<dim3(8, 32), 512, 0, stream>>>(qws, kws, vtg, ows);
    gemm_bt<float><<<dim3(8, 32), 256, 0, stream>>>(ows, woutT, (float*)d_out, 1024, 1024);
}